// Round 5
// baseline (957.077 us; speedup 1.0000x reference)
//
#include <hip/hip_runtime.h>
#include <hip/hip_bf16.h>

// ---------------------------------------------------------------------------
// GNN encoder for MI355X — R5: fix B-fragment register residency.
// R4 evidence: VGPR_Count=120 < 128 needed for B[8][4] alone -> compiler was
// re-loading W2 fragments from global inside the phase-2 loop (8 serialized
// L2 round-trips/tile = the hidden 37k cyc/tile). Fix: split GEMM2 K=128 into
// two K=64 halves so live B = 64 VGPRs; launch_bounds(256,4); nfT in bf16
// (LDS 52KB -> 3 blocks/CU); ea loads hoisted above the node gather.
// ---------------------------------------------------------------------------

#define NN 20000
#define NE 400000

typedef unsigned short u16;
typedef unsigned int   u32;
typedef __attribute__((ext_vector_type(8))) short short8;
typedef __attribute__((ext_vector_type(4))) short short4v;
typedef __attribute__((ext_vector_type(4))) float f32x4;

__device__ __forceinline__ float bf2f(u16 h) {
  union { u32 u; float f; } v; v.u = ((u32)h) << 16; return v.f;
}
__device__ __forceinline__ u16 f2bf(float f) {
  union { float f; u32 u; } v; v.f = f;
  return (u16)((v.u + 0x7FFFu + ((v.u >> 16) & 1u)) >> 16);
}
__device__ __forceinline__ float ldf(const void* p, size_t i, int f32m) {
  return f32m ? ((const float*)p)[i] : bf2f(((const u16*)p)[i]);
}
__device__ __forceinline__ int ldi(const void* p, size_t i, int i64m) {
  return i64m ? (int)((const long long*)p)[i] : ((const int*)p)[i];
}
__device__ __forceinline__ void stf(void* p, size_t i, float v, int f32m) {
  if (f32m) ((float*)p)[i] = v; else ((u16*)p)[i] = f2bf(v);
}

// --- dtype detection (flags pre-zeroed by memset) --------------------------
__global__ void k_detect(const u16* __restrict__ x16,
                         const int* __restrict__ ei32, int* __restrict__ flags) {
  int t = blockIdx.x * 256 + threadIdx.x;
  int found_f32 = 0, found_hi = 0;
  for (int i = t; i < NN * 16; i += 64 * 256) {
    u16 v = x16[i];
    if ((v & 0x7F80u) == 0x7F80u) found_f32 = 1;  // Inf/NaN pattern: only f32 halves
  }
  for (int i = t; i < 200000; i += 64 * 256)
    if (ei32[2 * i + 1] != 0) found_hi = 1;
  if (__any(found_f32) && (threadIdx.x & 63) == 0) atomicOr(&flags[0], 1);
  if (__any(found_hi) && (threadIdx.x & 63) == 0) atomicOr(&flags[1], 1);
}

// --- pack W2 [128,512] into MFMA B-fragment order -------------------------
__global__ void k_pack_w2(const void* __restrict__ W2, u16* __restrict__ w2p,
                          const int* __restrict__ flags) {
  const int f32m = flags[0];
  int t = blockIdx.x * 256 + threadIdx.x;          // 32*4*64 = 8192
  if (t >= 32 * 4 * 64) return;
  int lane = t & 63;
  int ks = (t >> 6) & 3;
  int kb = t >> 8;
  int n = lane & 15, q = lane >> 4;
  for (int j = 0; j < 8; ++j) {
    int h = ks * 32 + q * 8 + j;
    w2p[(size_t)t * 8 + j] = f2bf(ldf(W2, (size_t)h * 512 + kb * 16 + n, f32m));
  }
}

// --- pack W1 [16,128] zero-padded to K=32 into B-fragment order -----------
__global__ void k_pack_w1(const void* __restrict__ W1, u16* __restrict__ w1p,
                          const int* __restrict__ flags) {
  const int f32m = flags[0];
  int t = blockIdx.x * 256 + threadIdx.x;          // 8*64 = 512
  if (t >= 8 * 64) return;
  int lane = t & 63;
  int n = t >> 6;
  int col = n * 16 + (lane & 15), q = lane >> 4;
  for (int j = 0; j < 8; ++j) {
    int kk = q * 8 + j;
    w1p[(size_t)t * 8 + j] = (kk < 16) ? f2bf(ldf(W1, (size_t)kk * 128 + col, f32m)) : (u16)0;
  }
}

// --- node embedding: h0 = relu(x @ Wn + bn) -------------------------------
__global__ void k_embed(const void* __restrict__ x, const void* __restrict__ Wn,
                        const void* __restrict__ bn, float* __restrict__ h0,
                        const int* __restrict__ flags) {
  const int f32m = flags[0];
  int t = blockIdx.x * 256 + threadIdx.x;
  if (t >= NN * 16) return;
  int n = t >> 4, d = t & 15;
  float acc = ldf(bn, d, f32m);
  for (int k = 0; k < 16; ++k)
    acc += ldf(x, n * 16 + k, f32m) * ldf(Wn, k * 16 + d, f32m);
  h0[t] = fmaxf(acc, 0.f);
}

// --- CSR build -------------------------------------------------------------
__global__ void k_count(const void* __restrict__ ei, int* __restrict__ cnt,
                        const int* __restrict__ flags) {
  const int i64m = !flags[1];
  int i = blockIdx.x * 256 + threadIdx.x;
  if (i < NE) atomicAdd(&cnt[ldi(ei, NE + i, i64m)], 1);
}

__global__ void k_scan(const int* __restrict__ cnt, int* __restrict__ rowptr,
                       int* __restrict__ cursor) {
  __shared__ int part[1024];
  int t = threadIdx.x;
  int base = t * 20;                               // 1024*20 = 20480 >= NN
  int s = 0;
  for (int j = 0; j < 20; ++j) { int idx = base + j; if (idx < NN) s += cnt[idx]; }
  part[t] = s;
  __syncthreads();
  for (int off = 1; off < 1024; off <<= 1) {
    int v = (t >= off) ? part[t - off] : 0;
    __syncthreads();
    part[t] += v;
    __syncthreads();
  }
  int run = t ? part[t - 1] : 0;
  for (int j = 0; j < 20; ++j) {
    int idx = base + j;
    if (idx < NN) {
      int c = cnt[idx];                            // read BEFORE cursor aliasing write
      rowptr[idx] = run; cursor[idx] = run; run += c;
    }
  }
  if (t == 1023) rowptr[NN] = part[1023];
}

// stores inv[e] = CSR slot of edge e (msg written permuted, gather contiguous)
__global__ void k_scatter(const void* __restrict__ ei, int* __restrict__ cursor,
                          int* __restrict__ inv, const int* __restrict__ flags) {
  const int i64m = !flags[1];
  int i = blockIdx.x * 256 + threadIdx.x;
  if (i >= NE) return;
  int d = ldi(ei, NE + i, i64m);
  int pos = atomicAdd(&cursor[d], 1);
  inv[i] = pos;
}

// --- fused edge kernel: one 128-edge tile per block -----------------------
__launch_bounds__(256, 4)
__global__ void k_edge(const void* __restrict__ ea, const void* __restrict__ ei,
                       const float* __restrict__ hprev,
                       const u16* __restrict__ w2p, const u16* __restrict__ w1p,
                       const void* __restrict__ b1, const void* __restrict__ b2,
                       u16* __restrict__ msg16, float* __restrict__ aggr,
                       const int* __restrict__ inv,
                       const int* __restrict__ flags, int use_csr) {
  __shared__ u16   a2_lds[128 * 132];   // 33792 B; bank-stride 66 ≡ 2 mod 32
  __shared__ u16   nfT[32 * 132];       //  8448 B; nfT[kb][edge] bf16
  __shared__ float msg_lds[128 * 17];   //  8704 B
  __shared__ float b1_lds[128];
  __shared__ int   dst_lds[128];        // total ~51.9 KB -> 3 blocks/CU

  const int f32m = flags[0], i64m = !flags[1];
  const int t = threadIdx.x;
  const int lane = t & 63, w = t >> 6;
  const int q = lane >> 4, l16 = lane & 15;
  const int e0 = blockIdx.x * 128;

  // --- hoisted ea A-fragment loads (latency hides under node gather) ------
  union { short8 s; u16 h[8]; } ua[2];
#pragma unroll
  for (int mm = 0; mm < 2; ++mm) {
    int m = w * 2 + mm;
    if (q < 2) {
      if (f32m) {
        const float* er = (const float*)ea + ((size_t)(e0 + m * 16 + l16) * 16 + q * 8);
        float4 f0 = *(const float4*)er;
        float4 f1 = *(const float4*)(er + 4);
        ua[mm].h[0] = f2bf(f0.x); ua[mm].h[1] = f2bf(f0.y);
        ua[mm].h[2] = f2bf(f0.z); ua[mm].h[3] = f2bf(f0.w);
        ua[mm].h[4] = f2bf(f1.x); ua[mm].h[5] = f2bf(f1.y);
        ua[mm].h[6] = f2bf(f1.z); ua[mm].h[7] = f2bf(f1.w);
      } else {
        ua[mm].s = *(const short8*)((const u16*)ea + ((size_t)(e0 + m * 16 + l16) * 16 + q * 8));
      }
    } else {
#pragma unroll
      for (int j = 0; j < 8; ++j) ua[mm].h[j] = 0;
    }
  }

  float b2v[8];
#pragma unroll
  for (int i = 0; i < 8; ++i) b2v[i] = ldf(b2, (w * 8 + i) * 16 + l16, f32m);
  short8 W1f[8];
  {
    const short8* w1pf = (const short8*)w1p;
#pragma unroll
    for (int n = 0; n < 8; ++n) W1f[n] = w1pf[n * 64 + lane];
  }
  if (t < 128) b1_lds[t] = ldf(b1, t, f32m);

  {  // phase 0: gather nf -> transposed bf16 LDS, dst slot, zero msg
    int e = t >> 1, hh = t & 1;               // hh=0 -> dst, hh=1 -> src
    int node = hh ? ldi(ei, e0 + e, i64m) : ldi(ei, NE + e0 + e, i64m);
    const float4* hp = (const float4*)(hprev + (size_t)node * 16);
    float4 h0v = hp[0], h1v = hp[1], h2v = hp[2], h3v = hp[3];
    u16* col = nfT + (size_t)(hh * 16) * 132 + e;
    col[0 * 132] = f2bf(h0v.x); col[1 * 132] = f2bf(h0v.y);
    col[2 * 132] = f2bf(h0v.z); col[3 * 132] = f2bf(h0v.w);
    col[4 * 132] = f2bf(h1v.x); col[5 * 132] = f2bf(h1v.y);
    col[6 * 132] = f2bf(h1v.z); col[7 * 132] = f2bf(h1v.w);
    col[8 * 132] = f2bf(h2v.x); col[9 * 132] = f2bf(h2v.y);
    col[10 * 132] = f2bf(h2v.z); col[11 * 132] = f2bf(h2v.w);
    col[12 * 132] = f2bf(h3v.x); col[13 * 132] = f2bf(h3v.y);
    col[14 * 132] = f2bf(h3v.z); col[15 * 132] = f2bf(h3v.w);
    if (!hh) {
      if (use_csr) dst_lds[e] = inv[e0 + e];
      else         dst_lds[e] = node;
    }
    float* mz = msg_lds + e * 17 + hh * 8;
#pragma unroll
    for (int k2 = 0; k2 < 8; ++k2) mz[k2] = 0.f;
  }
  __syncthreads();

  // phase 1: A2 = relu(ea@W1+b1) -> bf16 LDS
#pragma unroll
  for (int mm = 0; mm < 2; ++mm) {
    int m = w * 2 + mm;
    short8 A = ua[mm].s;
#pragma unroll
    for (int n = 0; n < 8; ++n) {
      f32x4 c = {0.f, 0.f, 0.f, 0.f};
      c = __builtin_amdgcn_mfma_f32_16x16x32_bf16(A, W1f[n], c, 0, 0, 0);
      float bb = b1_lds[n * 16 + l16];
#pragma unroll
      for (int r = 0; r < 4; ++r)
        a2_lds[(m * 16 + q * 4 + r) * 132 + n * 16 + l16] =
            f2bf(fmaxf(c[r] + bb, 0.f));
    }
  }
  __syncthreads();

  // phase 2: msg = sum_kb nf[:,kb]*(A2@W2_kb + b2_kb)
  // K=128 split into two K=64 halves -> live B = 16 short8 = 64 VGPRs (fits
  // the launch_bounds(256,4) 128-reg cap; no compiler reload-rematerialize).
#pragma unroll 1
  for (int hf = 0; hf < 2; ++hf) {
    short8 Bh[8][2];
    {
      const short8* w2pf = (const short8*)w2p;
#pragma unroll
      for (int i = 0; i < 8; ++i)
#pragma unroll
        for (int s = 0; s < 2; ++s)
          Bh[i][s] = w2pf[((w * 8 + i) * 4 + (2 * hf + s)) * 64 + lane];
    }
#pragma unroll 1
    for (int mi = 0; mi < 8; ++mi) {
      int m = (mi + w * 2) & 7;  // stagger to decorrelate LDS traffic
      const u16* arow = &a2_lds[(m * 16 + l16) * 132 + q * 8];
      short8 A0 = *(const short8*)(arow + hf * 64);
      short8 A1 = *(const short8*)(arow + hf * 64 + 32);
      float mr0 = 0.f, mr1 = 0.f, mr2 = 0.f, mr3 = 0.f;
#pragma unroll
      for (int i = 0; i < 8; ++i) {
        f32x4 c;
        if (hf == 0) { c[0] = b2v[i]; c[1] = b2v[i]; c[2] = b2v[i]; c[3] = b2v[i]; }
        else         { c[0] = 0.f;    c[1] = 0.f;    c[2] = 0.f;    c[3] = 0.f;    }
        c = __builtin_amdgcn_mfma_f32_16x16x32_bf16(A0, Bh[i][0], c, 0, 0, 0);
        c = __builtin_amdgcn_mfma_f32_16x16x32_bf16(A1, Bh[i][1], c, 0, 0, 0);
        int kb = w * 8 + i;
        short4v nf4 = *(const short4v*)&nfT[(size_t)kb * 132 + m * 16 + q * 4];
        mr0 += bf2f((u16)nf4[0]) * c[0];
        mr1 += bf2f((u16)nf4[1]) * c[1];
        mr2 += bf2f((u16)nf4[2]) * c[2];
        mr3 += bf2f((u16)nf4[3]) * c[3];
      }
      int eb = (m * 16 + q * 4) * 17 + l16;
      atomicAdd(&msg_lds[eb + 0 * 17], mr0);
      atomicAdd(&msg_lds[eb + 1 * 17], mr1);
      atomicAdd(&msg_lds[eb + 2 * 17], mr2);
      atomicAdd(&msg_lds[eb + 3 * 17], mr3);
    }
  }
  __syncthreads();

  {  // epilogue
    int e = t >> 1, dh = t & 1;
    const float* mp = msg_lds + e * 17 + dh * 8;
    if (use_csr) {  // bf16 msg at CSR slot -> k_gather reads contiguously
      int pos = dst_lds[e];
      union { uint4 qv; u16 h[8]; } pk;
#pragma unroll
      for (int dd = 0; dd < 8; ++dd) pk.h[dd] = f2bf(mp[dd]);
      *(uint4*)(msg16 + (size_t)pos * 16 + dh * 8) = pk.qv;
    } else {        // fallback: scatter atomics to aggr[dst]
      int dnode = dst_lds[e];
      float* ap2 = aggr + (size_t)dnode * 16 + dh * 8;
#pragma unroll
      for (int dd = 0; dd < 8; ++dd) atomicAdd(ap2 + dd, mp[dd]);
    }
  }
}

// --- gather + combine: h_new = csr_sum(msg) + h_old @ root + bias ---------
__global__ void k_gather(const u16* __restrict__ msg16,
                         const int* __restrict__ rowptr,
                         const float* __restrict__ h_old,
                         const void* __restrict__ root,
                         const void* __restrict__ bias,
                         float* __restrict__ h_new, void* __restrict__ out,
                         const int* __restrict__ flags) {
  const int f32m = flags[0];
  __shared__ float R[256];
  __shared__ float Bv[16];
  int tt = threadIdx.x;
  R[tt] = ldf(root, tt, f32m);
  if (tt < 16) Bv[tt] = ldf(bias, tt, f32m);
  __syncthreads();
  int t = blockIdx.x * 256 + tt;
  if (t >= NN * 16) return;
  int n = t >> 4, d = t & 15;
  float acc = Bv[d];
#pragma unroll
  for (int k = 0; k < 16; ++k) acc += h_old[n * 16 + k] * R[k * 16 + d];
  int beg = rowptr[n], end = rowptr[n + 1];
  for (int i = beg; i < end; ++i)          // contiguous bf16 rows
    acc += bf2f(msg16[(size_t)i * 16 + d]);
  if (h_new) h_new[t] = acc;
  else       stf(out, t, acc, f32m);
}

// --- fallback combine (non-CSR path) --------------------------------------
__global__ void k_combine(const float* __restrict__ h_old,
                          const float* __restrict__ aggr,
                          const void* __restrict__ root,
                          const void* __restrict__ bias,
                          float* __restrict__ h_new, void* __restrict__ out,
                          const int* __restrict__ flags) {
  const int f32m = flags[0];
  int t = blockIdx.x * 256 + threadIdx.x;
  if (t >= NN * 16) return;
  int n = t >> 4, d = t & 15;
  float acc = aggr[t] + ldf(bias, d, f32m);
  for (int k = 0; k < 16; ++k)
    acc += h_old[n * 16 + k] * ldf(root, (size_t)k * 16 + d, f32m);
  if (h_new) h_new[t] = acc;
  else       stf(out, t, acc, f32m);
}

// --- edge embedding + log_softmax -----------------------------------------
__global__ void k_ee(const void* __restrict__ ea, const void* __restrict__ We,
                     const void* __restrict__ be, void* __restrict__ out,
                     const int* __restrict__ flags) {
  const int f32m = flags[0];
  __shared__ float W[256];
  __shared__ float Bv[16];
  int t = threadIdx.x;
  W[t] = ldf(We, t, f32m);
  if (t < 16) Bv[t] = ldf(be, t, f32m);
  __syncthreads();
  int e = blockIdx.x * 256 + t;
  if (e >= NE) return;
  float v[16];
  if (f32m) {
    const float4* ep = (const float4*)((const float*)ea + (size_t)e * 16);
    float4 r0 = ep[0], r1 = ep[1], r2 = ep[2], r3 = ep[3];
    v[0]=r0.x; v[1]=r0.y; v[2]=r0.z; v[3]=r0.w;
    v[4]=r1.x; v[5]=r1.y; v[6]=r1.z; v[7]=r1.w;
    v[8]=r2.x; v[9]=r2.y; v[10]=r2.z; v[11]=r2.w;
    v[12]=r3.x; v[13]=r3.y; v[14]=r3.z; v[15]=r3.w;
  } else {
    union { uint4 qv[2]; u16 h[16]; } rw;
    const uint4* ep = (const uint4*)((const u16*)ea + (size_t)e * 16);
    rw.qv[0] = ep[0]; rw.qv[1] = ep[1];
#pragma unroll
    for (int k = 0; k < 16; ++k) v[k] = bf2f(rw.h[k]);
  }
  float o[16];
  float mx = 0.f;
#pragma unroll
  for (int d = 0; d < 16; ++d) {
    float acc = Bv[d];
#pragma unroll
    for (int k = 0; k < 16; ++k) acc += v[k] * W[k * 16 + d];
    acc = fmaxf(acc, 0.f);
    o[d] = acc;
    mx = fmaxf(mx, acc);
  }
  float s = 0.f;
#pragma unroll
  for (int d = 0; d < 16; ++d) s += __expf(o[d] - mx);
  float lse = mx + __logf(s);
  const size_t off_ee = 1120000, off_ls = 7520000;
  if (f32m) {
    union { float4 fv; float f[4]; } pe, pl;
    float* oe = (float*)out + off_ee + (size_t)e * 16;
    float* ol = (float*)out + off_ls + (size_t)e * 16;
#pragma unroll
    for (int g = 0; g < 4; ++g) {
#pragma unroll
      for (int d = 0; d < 4; ++d) { pe.f[d] = o[g*4+d]; pl.f[d] = o[g*4+d] - lse; }
      ((float4*)oe)[g] = pe.fv;
      ((float4*)ol)[g] = pl.fv;
    }
  } else {
    union { uint4 qv[2]; u16 h[16]; } pe, pl;
#pragma unroll
    for (int d = 0; d < 16; ++d) {
      pe.h[d] = f2bf(o[d]);
      pl.h[d] = f2bf(o[d] - lse);
    }
    uint4* oe = (uint4*)((u16*)out + off_ee + (size_t)e * 16);
    uint4* ol = (uint4*)((u16*)out + off_ls + (size_t)e * 16);
    oe[0] = pe.qv[0]; oe[1] = pe.qv[1];
    ol[0] = pl.qv[0]; ol[1] = pl.qv[1];
  }
}

// --- edge_index passthrough -----------------------------------------------
__global__ void k_idx(const void* __restrict__ ei, void* __restrict__ out,
                      const int* __restrict__ flags) {
  const int f32m = flags[0], i64m = !flags[1];
  int i = blockIdx.x * 256 + threadIdx.x;
  if (i >= 2 * NE) return;
  float v = i64m ? (float)((const long long*)ei)[i] : (float)((const int*)ei)[i];
  stf(out, (size_t)320000 + i, v, f32m);
}

extern "C" void kernel_launch(void* const* d_in, const int* in_sizes, int n_in,
                              void* d_out, int out_size, void* d_ws, size_t ws_size,
                              hipStream_t stream) {
  const void* x     = d_in[0];
  const void* ei    = d_in[1];
  const void* ea    = d_in[2];
  const void* Wn    = d_in[3];
  const void* bn    = d_in[4];
  const void* We    = d_in[5];
  const void* be    = d_in[6];
  const void* W1    = d_in[7];
  const void* b1    = d_in[8];
  const void* W2    = d_in[9];
  const void* b2    = d_in[10];
  const void* root1 = d_in[11];
  const void* bias1 = d_in[12];
  const void* root2 = d_in[13];
  const void* bias2 = d_in[14];

  char* ws = (char*)d_ws;
  int*   flags = (int*)ws;                              // @0, 16 B
  float* h0     = (float*)(ws + 16);                    // 1,280,000 B
  float* h1     = (float*)(ws + 1280016);               // 1,280,000 B
  u16*   w2p    = (u16*)(ws + 2560016);                 //   131,072 B
  u16*   w1p    = (u16*)(ws + 2691088);                 //     8,192 B
  u16*   msg16  = (u16*)(ws + 2699280);                 // 12,800,000 B
  int*   rowptr = (int*)(ws + 15499280);                //     80,016 B
  int*   cursor = (int*)(ws + 15579296);                //     80,000 B
  int*   inv    = (int*)(ws + 15659296);                //  1,600,000 B
  const size_t need_csr = 17259296;
  float* aggr = (float*)(ws + 2699280);                 // fallback aliases msg16
  const int use_csr = (ws_size >= need_csr) ? 1 : 0;

  hipMemsetAsync(flags, 0, 16, stream);
  k_detect<<<64, 256, 0, stream>>>((const u16*)x, (const int*)ei, flags);
  k_pack_w2<<<32, 256, 0, stream>>>(W2, w2p, flags);
  k_pack_w1<<<2, 256, 0, stream>>>(W1, w1p, flags);
  k_embed<<<1250, 256, 0, stream>>>(x, Wn, bn, h0, flags);

  if (use_csr) {
    hipMemsetAsync(cursor, 0, NN * 4, stream);
    k_count<<<1563, 256, 0, stream>>>(ei, cursor, flags);
    k_scan<<<1, 1024, 0, stream>>>(cursor, rowptr, cursor);
    k_scatter<<<1563, 256, 0, stream>>>(ei, cursor, inv, flags);

    k_edge<<<3125, 256, 0, stream>>>(ea, ei, h0, w2p, w1p, b1, b2, msg16, nullptr, inv, flags, 1);
    k_gather<<<1250, 256, 0, stream>>>(msg16, rowptr, h0, root1, bias1, h1, nullptr, flags);
    k_edge<<<3125, 256, 0, stream>>>(ea, ei, h1, w2p, w1p, b1, b2, msg16, nullptr, inv, flags, 1);
    k_gather<<<1250, 256, 0, stream>>>(msg16, rowptr, h1, root2, bias2, nullptr, d_out, flags);
  } else {
    hipMemsetAsync(aggr, 0, (size_t)NN * 16 * 4, stream);
    k_edge<<<3125, 256, 0, stream>>>(ea, ei, h0, w2p, w1p, b1, b2, nullptr, aggr, nullptr, flags, 0);
    k_combine<<<1250, 256, 0, stream>>>(h0, aggr, root1, bias1, h1, nullptr, flags);
    hipMemsetAsync(aggr, 0, (size_t)NN * 16 * 4, stream);
    k_edge<<<3125, 256, 0, stream>>>(ea, ei, h1, w2p, w1p, b1, b2, nullptr, aggr, nullptr, flags, 0);
    k_combine<<<1250, 256, 0, stream>>>(h1, aggr, root2, bias2, nullptr, d_out, flags);
  }

  k_ee<<<1563, 256, 0, stream>>>(ea, We, be, d_out, flags);
  k_idx<<<3125, 256, 0, stream>>>(ei, d_out, flags);
}

// Round 6
// 648.398 us; speedup vs baseline: 1.4761x; 1.4761x over previous
//
#include <hip/hip_runtime.h>
#include <hip/hip_bf16.h>

// ---------------------------------------------------------------------------
// GNN encoder MI355X — R6.
// R5 lesson: split-K reload structure doubled stall at constant MFMA work.
// R6: phase-2 loop interchange (kb-chunk outer, m inner, mr[8][4] resident)
// -> ~110 VGPR live, no spill/reload; 3 blocks/CU (LDS 52,992); aux kernels
// fused into k_prep / k_final with self-detected dtypes.
// ---------------------------------------------------------------------------

#define NN 20000
#define NE 400000

typedef unsigned short u16;
typedef unsigned int   u32;
typedef __attribute__((ext_vector_type(8))) short short8;
typedef __attribute__((ext_vector_type(4))) short short4v;
typedef __attribute__((ext_vector_type(4))) float f32x4;

__device__ __forceinline__ float bf2f(u16 h) {
  union { u32 u; float f; } v; v.u = ((u32)h) << 16; return v.f;
}
__device__ __forceinline__ u16 f2bf(float f) {
  union { float f; u32 u; } v; v.f = f;
  return (u16)((v.u + 0x7FFFu + ((v.u >> 16) & 1u)) >> 16);
}
__device__ __forceinline__ float ldf(const void* p, size_t i, int f32m) {
  return f32m ? ((const float*)p)[i] : bf2f(((const u16*)p)[i]);
}
__device__ __forceinline__ int ldi(const void* p, size_t i, int i64m) {
  return i64m ? (int)((const long long*)p)[i] : ((const int*)p)[i];
}
__device__ __forceinline__ void stf(void* p, size_t i, float v, int f32m) {
  if (f32m) ((float*)p)[i] = v; else ((u16*)p)[i] = f2bf(v);
}

// --- self-detection helpers (wave-uniform; P(miss) ~ e^-32) ----------------
__device__ __forceinline__ u32 nanpat(u32 w) {
  return (((w & 0x7F80u) == 0x7F80u) || ((w & 0x7F800000u) == 0x7F800000u)) ? 1u : 0u;
}
// 1 iff float data is f32 (scan first 8192 u16 of a LARGE tensor)
__device__ __forceinline__ int det_f32(const u16* p) {
  const uint4* q4 = (const uint4*)p;
  int lane = threadIdx.x & 63;
  u32 bad = 0;
  for (int it = 0; it < 16; ++it) {
    uint4 v = q4[it * 64 + lane];
    bad |= nanpat(v.x) | nanpat(v.y) | nanpat(v.z) | nanpat(v.w);
  }
  return __any(bad) ? 1 : 0;
}
// 1 iff edge_index is int32 (odd int32 slots of first 512 i64-slots nonzero)
__device__ __forceinline__ int det_i32(const int* e) {
  int lane = threadIdx.x & 63;
  int nz = 0;
  for (int it = 0; it < 8; ++it) nz |= e[(it * 64 + lane) * 2 + 1];
  return __any(nz) ? 1 : 0;
}

// --- K1: fused prep: idx | count | embed | pack_w2 | pack_w1 | flag-detect -
__global__ void k_prep(const void* __restrict__ x, const void* __restrict__ ei,
                       const void* __restrict__ W1, const void* __restrict__ W2,
                       const void* __restrict__ Wn, const void* __restrict__ bn,
                       float* __restrict__ h0, u16* __restrict__ w2p,
                       u16* __restrict__ w1p, int* __restrict__ cnt,
                       void* __restrict__ out, int* __restrict__ flags,
                       int use_csr) {
  const int b = blockIdx.x, t = threadIdx.x;
  if (b < 3125) {                      // edge_index passthrough -> out
    int f32m = det_f32((const u16*)x);
    int i64m = !det_i32((const int*)ei);
    int i = b * 256 + t;               // < 800000 exactly
    float v = i64m ? (float)((const long long*)ei)[i] : (float)((const int*)ei)[i];
    stf(out, (size_t)320000 + i, v, f32m);
  } else if (b < 4688) {               // CSR count
    if (!use_csr) return;
    int i64m = !det_i32((const int*)ei);
    int i = (b - 3125) * 256 + t;
    if (i < NE) atomicAdd(&cnt[ldi(ei, NE + i, i64m)], 1);
  } else if (b < 5938) {               // node embedding
    int f32m = det_f32((const u16*)x);
    int i = (b - 4688) * 256 + t;      // < 320000
    int n = i >> 4, d = i & 15;
    float acc = ldf(bn, d, f32m);
    for (int k = 0; k < 16; ++k)
      acc += ldf(x, n * 16 + k, f32m) * ldf(Wn, k * 16 + d, f32m);
    h0[i] = fmaxf(acc, 0.f);
  } else if (b < 5970) {               // pack W2 -> B-fragment order
    int f32m = det_f32((const u16*)W2);
    int i = (b - 5938) * 256 + t;      // < 8192
    int lane = i & 63, ks = (i >> 6) & 3, kb = i >> 8;
    int n = lane & 15, qq = lane >> 4;
    for (int j = 0; j < 8; ++j) {
      int hrow = ks * 32 + qq * 8 + j;
      w2p[(size_t)i * 8 + j] = f2bf(ldf(W2, (size_t)hrow * 512 + kb * 16 + n, f32m));
    }
  } else if (b < 5972) {               // pack W1 (zero-padded K=32)
    int f32m = det_f32((const u16*)W2);
    int i = (b - 5970) * 256 + t;      // < 512
    int lane = i & 63, n = i >> 6;
    int col = n * 16 + (lane & 15), qq = lane >> 4;
    for (int j = 0; j < 8; ++j) {
      int kk = qq * 8 + j;
      w1p[(size_t)i * 8 + j] = (kk < 16) ? f2bf(ldf(W1, (size_t)kk * 128 + col, f32m)) : (u16)0;
    }
  } else {                             // 64 detect blocks -> flags
    int tt = (b - 5972) * 256 + t;
    int found_f32 = 0, found_hi = 0;
    const u16* x16 = (const u16*)x;
    for (int i = tt; i < NN * 16; i += 64 * 256) {
      u16 v = x16[i];
      if ((v & 0x7F80u) == 0x7F80u) found_f32 = 1;
    }
    const int* e32 = (const int*)ei;
    for (int i = tt; i < 200000; i += 64 * 256)
      if (e32[2 * i + 1] != 0) found_hi = 1;
    if (__any(found_f32) && (t & 63) == 0) atomicOr(&flags[0], 1);
    if (__any(found_hi) && (t & 63) == 0) atomicOr(&flags[1], 1);
  }
}

// --- K2: exclusive scan over counts -> rowptr, cursor ----------------------
__global__ void k_scan(const int* __restrict__ cnt, int* __restrict__ rowptr,
                       int* __restrict__ cursor) {
  __shared__ int part[1024];
  int t = threadIdx.x;
  int base = t * 20;                               // 1024*20 >= NN
  int s = 0;
  for (int j = 0; j < 20; ++j) { int idx = base + j; if (idx < NN) s += cnt[idx]; }
  part[t] = s;
  __syncthreads();
  for (int off = 1; off < 1024; off <<= 1) {
    int v = (t >= off) ? part[t - off] : 0;
    __syncthreads();
    part[t] += v;
    __syncthreads();
  }
  int run = t ? part[t - 1] : 0;
  for (int j = 0; j < 20; ++j) {
    int idx = base + j;
    if (idx < NN) {
      int c = cnt[idx];                            // read BEFORE aliasing write
      rowptr[idx] = run; cursor[idx] = run; run += c;
    }
  }
  if (t == 1023) rowptr[NN] = part[1023];
}

// --- K3: inv[e] = CSR slot of edge e --------------------------------------
__global__ void k_scatter(const void* __restrict__ ei, int* __restrict__ cursor,
                          int* __restrict__ inv, const int* __restrict__ flags) {
  const int i64m = !flags[1];
  int i = blockIdx.x * 256 + threadIdx.x;
  if (i >= NE) return;
  int d = ldi(ei, NE + i, i64m);
  int pos = atomicAdd(&cursor[d], 1);
  inv[i] = pos;
}

// --- K4/K6: fused edge kernel, one 128-edge tile per block ----------------
__launch_bounds__(256, 4)
__global__ void k_edge(const void* __restrict__ ea, const void* __restrict__ ei,
                       const float* __restrict__ hprev,
                       const u16* __restrict__ w2p, const u16* __restrict__ w1p,
                       const void* __restrict__ b1, const void* __restrict__ b2,
                       u16* __restrict__ msg16, float* __restrict__ aggr,
                       const int* __restrict__ inv,
                       const int* __restrict__ flags, int use_csr) {
  __shared__ u16   a2_lds[128 * 136];   // 34816 B; 16B-aligned rows (R4-proven)
  __shared__ u16   nfT[32 * 132];       //  8448 B; nfT[kb][edge] bf16
  __shared__ float msg_lds[128 * 17];   //  8704 B
  __shared__ float b1_lds[128];
  __shared__ int   dst_lds[128];        // total 52992 B -> 3 blocks/CU

  const int f32m = flags[0], i64m = !flags[1];
  const int t = threadIdx.x;
  const int lane = t & 63, w = t >> 6;
  const int q = lane >> 4, l16 = lane & 15;
  const int e0 = blockIdx.x * 128;

  // hoisted ea A-fragment loads (latency hides under the node gather)
  union { short8 s; u16 h[8]; } ua[2];
#pragma unroll
  for (int mm = 0; mm < 2; ++mm) {
    int m = w * 2 + mm;
    if (q < 2) {
      if (f32m) {
        const float* er = (const float*)ea + ((size_t)(e0 + m * 16 + l16) * 16 + q * 8);
        float4 f0 = *(const float4*)er;
        float4 f1 = *(const float4*)(er + 4);
        ua[mm].h[0] = f2bf(f0.x); ua[mm].h[1] = f2bf(f0.y);
        ua[mm].h[2] = f2bf(f0.z); ua[mm].h[3] = f2bf(f0.w);
        ua[mm].h[4] = f2bf(f1.x); ua[mm].h[5] = f2bf(f1.y);
        ua[mm].h[6] = f2bf(f1.z); ua[mm].h[7] = f2bf(f1.w);
      } else {
        ua[mm].s = *(const short8*)((const u16*)ea + ((size_t)(e0 + m * 16 + l16) * 16 + q * 8));
      }
    } else {
#pragma unroll
      for (int j = 0; j < 8; ++j) ua[mm].h[j] = 0;
    }
  }

  float b2v[8];
#pragma unroll
  for (int i = 0; i < 8; ++i) b2v[i] = ldf(b2, (w * 8 + i) * 16 + l16, f32m);
  short8 W1f[8];
  {
    const short8* w1pf = (const short8*)w1p;
#pragma unroll
    for (int n = 0; n < 8; ++n) W1f[n] = w1pf[n * 64 + lane];
  }
  if (t < 128) b1_lds[t] = ldf(b1, t, f32m);

  {  // phase 0: gather nf -> transposed bf16 LDS; dst slot; zero msg
    int e = t >> 1, hh = t & 1;               // hh=0 -> dst, hh=1 -> src
    int node = hh ? ldi(ei, e0 + e, i64m) : ldi(ei, NE + e0 + e, i64m);
    const float4* hp = (const float4*)(hprev + (size_t)node * 16);
    float4 h0v = hp[0], h1v = hp[1], h2v = hp[2], h3v = hp[3];
    u16* col = nfT + (size_t)(hh * 16) * 132 + e;
    col[0 * 132] = f2bf(h0v.x); col[1 * 132] = f2bf(h0v.y);
    col[2 * 132] = f2bf(h0v.z); col[3 * 132] = f2bf(h0v.w);
    col[4 * 132] = f2bf(h1v.x); col[5 * 132] = f2bf(h1v.y);
    col[6 * 132] = f2bf(h1v.z); col[7 * 132] = f2bf(h1v.w);
    col[8 * 132] = f2bf(h2v.x); col[9 * 132] = f2bf(h2v.y);
    col[10 * 132] = f2bf(h2v.z); col[11 * 132] = f2bf(h2v.w);
    col[12 * 132] = f2bf(h3v.x); col[13 * 132] = f2bf(h3v.y);
    col[14 * 132] = f2bf(h3v.z); col[15 * 132] = f2bf(h3v.w);
    if (!hh) {
      if (use_csr) dst_lds[e] = inv[e0 + e];
      else         dst_lds[e] = node;
    }
    float* mz = msg_lds + e * 17 + hh * 8;
#pragma unroll
    for (int k2 = 0; k2 < 8; ++k2) mz[k2] = 0.f;
  }
  __syncthreads();

  // phase 1: A2 = relu(ea@W1+b1) -> bf16 LDS
#pragma unroll
  for (int mm = 0; mm < 2; ++mm) {
    int m = w * 2 + mm;
    short8 A = ua[mm].s;
#pragma unroll
    for (int n = 0; n < 8; ++n) {
      f32x4 c = {0.f, 0.f, 0.f, 0.f};
      c = __builtin_amdgcn_mfma_f32_16x16x32_bf16(A, W1f[n], c, 0, 0, 0);
      float bb = b1_lds[n * 16 + l16];
#pragma unroll
      for (int r = 0; r < 4; ++r)
        a2_lds[(m * 16 + q * 4 + r) * 136 + n * 16 + l16] =
            f2bf(fmaxf(c[r] + bb, 0.f));
    }
  }
  __syncthreads();

  // phase 2: kb-chunk OUTER (2 kb at a time), m INNER, mr[8][4] resident.
  // Live regs ~ Bc(32)+mr(32)+A(16)+misc -> fits 128-cap, no reload storms.
  float mr[8][4];
#pragma unroll
  for (int m = 0; m < 8; ++m)
#pragma unroll
    for (int r = 0; r < 4; ++r) mr[m][r] = 0.f;

  const short8* w2pf = (const short8*)w2p;
#pragma unroll 1
  for (int ic = 0; ic < 4; ++ic) {
    short8 Bc[2][4];
#pragma unroll
    for (int ii = 0; ii < 2; ++ii)
#pragma unroll
      for (int ks = 0; ks < 4; ++ks)
        Bc[ii][ks] = w2pf[((w * 8 + ic * 2 + ii) * 4 + ks) * 64 + lane];
#pragma unroll
    for (int m = 0; m < 8; ++m) {
      const u16* ar = &a2_lds[(m * 16 + l16) * 136 + q * 8];
      short8 A0 = *(const short8*)(ar);
      short8 A1 = *(const short8*)(ar + 32);
      short8 A2f = *(const short8*)(ar + 64);
      short8 A3 = *(const short8*)(ar + 96);
#pragma unroll
      for (int ii = 0; ii < 2; ++ii) {
        int i = ic * 2 + ii;
        f32x4 c = {b2v[i], b2v[i], b2v[i], b2v[i]};   // bias rides once per kb
        c = __builtin_amdgcn_mfma_f32_16x16x32_bf16(A0, Bc[ii][0], c, 0, 0, 0);
        c = __builtin_amdgcn_mfma_f32_16x16x32_bf16(A1, Bc[ii][1], c, 0, 0, 0);
        c = __builtin_amdgcn_mfma_f32_16x16x32_bf16(A2f, Bc[ii][2], c, 0, 0, 0);
        c = __builtin_amdgcn_mfma_f32_16x16x32_bf16(A3, Bc[ii][3], c, 0, 0, 0);
        int kb = w * 8 + i;
        short4v nf4 = *(const short4v*)&nfT[(size_t)kb * 132 + m * 16 + q * 4];
        mr[m][0] += bf2f((u16)nf4[0]) * c[0];
        mr[m][1] += bf2f((u16)nf4[1]) * c[1];
        mr[m][2] += bf2f((u16)nf4[2]) * c[2];
        mr[m][3] += bf2f((u16)nf4[3]) * c[3];
      }
    }
  }
  // cross-wave kb-reduction: one atomic block per tile (32 instrs/wave)
#pragma unroll
  for (int m = 0; m < 8; ++m) {
    int eb = (m * 16 + q * 4) * 17 + l16;
    atomicAdd(&msg_lds[eb + 0 * 17], mr[m][0]);
    atomicAdd(&msg_lds[eb + 1 * 17], mr[m][1]);
    atomicAdd(&msg_lds[eb + 2 * 17], mr[m][2]);
    atomicAdd(&msg_lds[eb + 3 * 17], mr[m][3]);
  }
  __syncthreads();

  {  // epilogue
    int e = t >> 1, dh = t & 1;
    const float* mp = msg_lds + e * 17 + dh * 8;
    if (use_csr) {  // bf16 msg at CSR slot -> k_gather reads contiguously
      int pos = dst_lds[e];
      union { uint4 qv; u16 h[8]; } pk;
#pragma unroll
      for (int dd = 0; dd < 8; ++dd) pk.h[dd] = f2bf(mp[dd]);
      *(uint4*)(msg16 + (size_t)pos * 16 + dh * 8) = pk.qv;
    } else {        // fallback: scatter atomics
      int dnode = dst_lds[e];
      float* ap2 = aggr + (size_t)dnode * 16 + dh * 8;
#pragma unroll
      for (int dd = 0; dd < 8; ++dd) atomicAdd(ap2 + dd, mp[dd]);
    }
  }
}

// --- K5: gather + combine (intermediate layer, f32 out) --------------------
__global__ void k_gather(const u16* __restrict__ msg16,
                         const int* __restrict__ rowptr,
                         const float* __restrict__ h_old,
                         const void* __restrict__ root,
                         const void* __restrict__ bias,
                         float* __restrict__ h_new,
                         const int* __restrict__ flags) {
  const int f32m = flags[0];
  __shared__ float R[256];
  __shared__ float Bv[16];
  int tt = threadIdx.x;
  R[tt] = ldf(root, tt, f32m);
  if (tt < 16) Bv[tt] = ldf(bias, tt, f32m);
  __syncthreads();
  int t = blockIdx.x * 256 + tt;
  if (t >= NN * 16) return;
  int n = t >> 4, d = t & 15;
  float acc = Bv[d];
#pragma unroll
  for (int k = 0; k < 16; ++k) acc += h_old[n * 16 + k] * R[k * 16 + d];
  int beg = rowptr[n], end = rowptr[n + 1];
  for (int i = beg; i < end; ++i)
    acc += bf2f(msg16[(size_t)i * 16 + d]);
  h_new[t] = acc;
}

// --- K7: fused final: gather2 -> out  |  ee + log_softmax -> out -----------
__global__ void k_final(const u16* __restrict__ msg16,
                        const int* __restrict__ rowptr,
                        const float* __restrict__ h_old,
                        const void* __restrict__ root,
                        const void* __restrict__ bias,
                        const void* __restrict__ ea, const void* __restrict__ We,
                        const void* __restrict__ be, void* __restrict__ out,
                        const int* __restrict__ flags) {
  const int f32m = flags[0];
  int tt = threadIdx.x;
  if (blockIdx.x < 1250) {             // ---- gather2 -> h output
    __shared__ float R[256];
    __shared__ float Bv[16];
    R[tt] = ldf(root, tt, f32m);
    if (tt < 16) Bv[tt] = ldf(bias, tt, f32m);
    __syncthreads();
    int t = blockIdx.x * 256 + tt;
    if (t >= NN * 16) return;
    int n = t >> 4, d = t & 15;
    float acc = Bv[d];
#pragma unroll
    for (int k = 0; k < 16; ++k) acc += h_old[n * 16 + k] * R[k * 16 + d];
    int beg = rowptr[n], end = rowptr[n + 1];
    for (int i = beg; i < end; ++i)
      acc += bf2f(msg16[(size_t)i * 16 + d]);
    stf(out, t, acc, f32m);
    return;
  }
  // ---- edge embedding + log_softmax
  __shared__ float W[256];
  __shared__ float Bv2[16];
  W[tt] = ldf(We, tt, f32m);
  if (tt < 16) Bv2[tt] = ldf(be, tt, f32m);
  __syncthreads();
  int e = (blockIdx.x - 1250) * 256 + tt;
  if (e >= NE) return;
  float v[16];
  if (f32m) {
    const float4* ep = (const float4*)((const float*)ea + (size_t)e * 16);
    float4 r0 = ep[0], r1 = ep[1], r2 = ep[2], r3 = ep[3];
    v[0]=r0.x; v[1]=r0.y; v[2]=r0.z; v[3]=r0.w;
    v[4]=r1.x; v[5]=r1.y; v[6]=r1.z; v[7]=r1.w;
    v[8]=r2.x; v[9]=r2.y; v[10]=r2.z; v[11]=r2.w;
    v[12]=r3.x; v[13]=r3.y; v[14]=r3.z; v[15]=r3.w;
  } else {
    union { uint4 qv[2]; u16 h[16]; } rw;
    const uint4* ep = (const uint4*)((const u16*)ea + (size_t)e * 16);
    rw.qv[0] = ep[0]; rw.qv[1] = ep[1];
#pragma unroll
    for (int k = 0; k < 16; ++k) v[k] = bf2f(rw.h[k]);
  }
  float o[16];
  float mx = 0.f;
#pragma unroll
  for (int d = 0; d < 16; ++d) {
    float acc = Bv2[d];
#pragma unroll
    for (int k = 0; k < 16; ++k) acc += v[k] * W[k * 16 + d];
    acc = fmaxf(acc, 0.f);
    o[d] = acc;
    mx = fmaxf(mx, acc);
  }
  float s = 0.f;
#pragma unroll
  for (int d = 0; d < 16; ++d) s += __expf(o[d] - mx);
  float lse = mx + __logf(s);
  const size_t off_ee = 1120000, off_ls = 7520000;
  if (f32m) {
    union { float4 fv; float f[4]; } pe, pl;
    float* oe = (float*)out + off_ee + (size_t)e * 16;
    float* ol = (float*)out + off_ls + (size_t)e * 16;
#pragma unroll
    for (int g = 0; g < 4; ++g) {
#pragma unroll
      for (int d = 0; d < 4; ++d) { pe.f[d] = o[g*4+d]; pl.f[d] = o[g*4+d] - lse; }
      ((float4*)oe)[g] = pe.fv;
      ((float4*)ol)[g] = pl.fv;
    }
  } else {
    union { uint4 qv[2]; u16 h[16]; } pe, pl;
#pragma unroll
    for (int d = 0; d < 16; ++d) {
      pe.h[d] = f2bf(o[d]);
      pl.h[d] = f2bf(o[d] - lse);
    }
    uint4* oe = (uint4*)((u16*)out + off_ee + (size_t)e * 16);
    uint4* ol = (uint4*)((u16*)out + off_ls + (size_t)e * 16);
    oe[0] = pe.qv[0]; oe[1] = pe.qv[1];
    ol[0] = pl.qv[0]; ol[1] = pl.qv[1];
  }
}

// --- fallback combine (non-CSR path) --------------------------------------
__global__ void k_combine(const float* __restrict__ h_old,
                          const float* __restrict__ aggr,
                          const void* __restrict__ root,
                          const void* __restrict__ bias,
                          float* __restrict__ h_new, void* __restrict__ out,
                          const int* __restrict__ flags) {
  const int f32m = flags[0];
  int t = blockIdx.x * 256 + threadIdx.x;
  if (t >= NN * 16) return;
  int n = t >> 4, d = t & 15;
  float acc = aggr[t] + ldf(bias, d, f32m);
  for (int k = 0; k < 16; ++k)
    acc += h_old[n * 16 + k] * ldf(root, (size_t)k * 16 + d, f32m);
  if (h_new) h_new[t] = acc;
  else       stf(out, t, acc, f32m);
}

// --- fallback ee (non-CSR path only) --------------------------------------
__global__ void k_ee(const void* __restrict__ ea, const void* __restrict__ We,
                     const void* __restrict__ be, void* __restrict__ out,
                     const int* __restrict__ flags) {
  // delegate to k_final's ee half by index math: block e-range starts at 0
  const int f32m = flags[0];
  __shared__ float W[256];
  __shared__ float Bv[16];
  int t = threadIdx.x;
  W[t] = ldf(We, t, f32m);
  if (t < 16) Bv[t] = ldf(be, t, f32m);
  __syncthreads();
  int e = blockIdx.x * 256 + t;
  if (e >= NE) return;
  float v[16];
#pragma unroll
  for (int k = 0; k < 16; ++k) v[k] = ldf(ea, (size_t)e * 16 + k, f32m);
  float o[16];
  float mx = 0.f;
#pragma unroll
  for (int d = 0; d < 16; ++d) {
    float acc = Bv[d];
#pragma unroll
    for (int k = 0; k < 16; ++k) acc += v[k] * W[k * 16 + d];
    acc = fmaxf(acc, 0.f);
    o[d] = acc; mx = fmaxf(mx, acc);
  }
  float s = 0.f;
#pragma unroll
  for (int d = 0; d < 16; ++d) s += __expf(o[d] - mx);
  float lse = mx + __logf(s);
#pragma unroll
  for (int d = 0; d < 16; ++d) {
    stf(out, 1120000 + (size_t)e * 16 + d, o[d], f32m);
    stf(out, 7520000 + (size_t)e * 16 + d, o[d] - lse, f32m);
  }
}

extern "C" void kernel_launch(void* const* d_in, const int* in_sizes, int n_in,
                              void* d_out, int out_size, void* d_ws, size_t ws_size,
                              hipStream_t stream) {
  const void* x     = d_in[0];
  const void* ei    = d_in[1];
  const void* ea    = d_in[2];
  const void* Wn    = d_in[3];
  const void* bn    = d_in[4];
  const void* We    = d_in[5];
  const void* be    = d_in[6];
  const void* W1    = d_in[7];
  const void* b1    = d_in[8];
  const void* W2    = d_in[9];
  const void* b2    = d_in[10];
  const void* root1 = d_in[11];
  const void* bias1 = d_in[12];
  const void* root2 = d_in[13];
  const void* bias2 = d_in[14];

  char* ws = (char*)d_ws;
  int*   flags  = (int*)ws;                             // @0, 16 B
  int*   cursor = (int*)(ws + 16);                      //    80,000 B (also cnt)
  float* h0     = (float*)(ws + 80016);                 // 1,280,000 B
  float* h1     = (float*)(ws + 1360016);               // 1,280,000 B
  u16*   w2p    = (u16*)(ws + 2640016);                 //   131,072 B
  u16*   w1p    = (u16*)(ws + 2771088);                 //     8,192 B
  u16*   msg16  = (u16*)(ws + 2779280);                 // 12,800,000 B
  int*   rowptr = (int*)(ws + 15579280);                //     80,016 B
  int*   inv    = (int*)(ws + 15659296);                //  1,600,000 B
  const size_t need_csr = 17259296;
  float* aggr = (float*)(ws + 2779280);                 // fallback aliases msg16
  const int use_csr = (ws_size >= need_csr) ? 1 : 0;

  // one memset covers flags + cursor (adjacent)
  hipMemsetAsync(ws, 0, use_csr ? 80016 : 16, stream);
  k_prep<<<6036, 256, 0, stream>>>(x, ei, W1, W2, Wn, bn, h0, w2p, w1p,
                                   cursor, d_out, flags, use_csr);

  if (use_csr) {
    k_scan<<<1, 1024, 0, stream>>>(cursor, rowptr, cursor);
    k_scatter<<<1563, 256, 0, stream>>>(ei, cursor, inv, flags);

    k_edge<<<3125, 256, 0, stream>>>(ea, ei, h0, w2p, w1p, b1, b2, msg16, nullptr, inv, flags, 1);
    k_gather<<<1250, 256, 0, stream>>>(msg16, rowptr, h0, root1, bias1, h1, flags);
    k_edge<<<3125, 256, 0, stream>>>(ea, ei, h1, w2p, w1p, b1, b2, msg16, nullptr, inv, flags, 1);
    k_final<<<2813, 256, 0, stream>>>(msg16, rowptr, h1, root2, bias2,
                                      ea, We, be, d_out, flags);
  } else {
    hipMemsetAsync(aggr, 0, (size_t)NN * 16 * 4, stream);
    k_edge<<<3125, 256, 0, stream>>>(ea, ei, h0, w2p, w1p, b1, b2, nullptr, aggr, nullptr, flags, 0);
    k_combine<<<1250, 256, 0, stream>>>(h0, aggr, root1, bias1, h1, nullptr, flags);
    hipMemsetAsync(aggr, 0, (size_t)NN * 16 * 4, stream);
    k_edge<<<3125, 256, 0, stream>>>(ea, ei, h1, w2p, w1p, b1, b2, nullptr, aggr, nullptr, flags, 0);
    k_combine<<<1250, 256, 0, stream>>>(h1, aggr, root2, bias2, nullptr, d_out, flags);
    k_ee<<<1563, 256, 0, stream>>>(ea, We, be, d_out, flags);
  }
}

// Round 8
// 625.188 us; speedup vs baseline: 1.5309x; 1.0371x over previous
//
#include <hip/hip_runtime.h>
#include <hip/hip_bf16.h>

// ---------------------------------------------------------------------------
// GNN encoder MI355X — R8 (= R7 + compile fix: nontemporal builtins need
// clang ext-vector types, not HIP_vector_type structs).
// R3-R6 invariant: occupancy ~21% (2 blocks/CU), 75% no-issue; per-tile serial
// latency is the clock. R7/R8: 4 blocks/CU via fp8-e4m3 A2/W2 in GEMM2
// (LDS 53->35KB, regs ~85 live), 2 barriers/tile (b1 in regs), nontemporal
// ea/msg to keep w2p L2-hot, ee fused into k_prep. GEMM1 stays bf16.
// ---------------------------------------------------------------------------

#define NN 20000
#define NE 400000

typedef unsigned short u16;
typedef unsigned int   u32;
typedef unsigned char  u8;
typedef long long      i64t;
typedef __attribute__((ext_vector_type(8))) short short8;
typedef __attribute__((ext_vector_type(4))) short short4v;
typedef __attribute__((ext_vector_type(4))) float f32x4;
typedef __attribute__((ext_vector_type(4))) unsigned int u32x4;

__device__ __forceinline__ float bf2f(u16 h) {
  union { u32 u; float f; } v; v.u = ((u32)h) << 16; return v.f;
}
__device__ __forceinline__ u16 f2bf(float f) {
  union { float f; u32 u; } v; v.f = f;
  return (u16)((v.u + 0x7FFFu + ((v.u >> 16) & 1u)) >> 16);
}
__device__ __forceinline__ float ldf(const void* p, size_t i, int f32m) {
  return f32m ? ((const float*)p)[i] : bf2f(((const u16*)p)[i]);
}
__device__ __forceinline__ int ldi(const void* p, size_t i, int i64m) {
  return i64m ? (int)((const long long*)p)[i] : ((const int*)p)[i];
}
__device__ __forceinline__ void stf(void* p, size_t i, float v, int f32m) {
  if (f32m) ((float*)p)[i] = v; else ((u16*)p)[i] = f2bf(v);
}
__device__ __forceinline__ u8 f2fp8(float v) {
  return (u8)(__builtin_amdgcn_cvt_pk_fp8_f32(v, v, 0, false) & 0xFF);
}

// --- self-detection helpers (wave-uniform; P(miss) ~ e^-32) ----------------
__device__ __forceinline__ u32 nanpat(u32 w) {
  return (((w & 0x7F80u) == 0x7F80u) || ((w & 0x7F800000u) == 0x7F800000u)) ? 1u : 0u;
}
__device__ __forceinline__ int det_f32(const u16* p) {
  const u32x4* q4 = (const u32x4*)p;
  int lane = threadIdx.x & 63;
  u32 bad = 0;
  for (int it = 0; it < 16; ++it) {
    u32x4 v = q4[it * 64 + lane];
    bad |= nanpat(v.x) | nanpat(v.y) | nanpat(v.z) | nanpat(v.w);
  }
  return __any(bad) ? 1 : 0;
}
__device__ __forceinline__ int det_i32(const int* e) {
  int lane = threadIdx.x & 63;
  int nz = 0;
  for (int it = 0; it < 8; ++it) nz |= e[(it * 64 + lane) * 2 + 1];
  return __any(nz) ? 1 : 0;
}

// --- K1: fused prep: idx | count | embed | packW2(fp8) | packW1 | detect | ee
__global__ void k_prep(const void* __restrict__ x, const void* __restrict__ ei,
                       const void* __restrict__ ea,
                       const void* __restrict__ W1, const void* __restrict__ W2,
                       const void* __restrict__ Wn, const void* __restrict__ bn,
                       const void* __restrict__ We, const void* __restrict__ be,
                       float* __restrict__ h0, u8* __restrict__ w2p8,
                       u16* __restrict__ w1p, int* __restrict__ cnt,
                       void* __restrict__ out, int* __restrict__ flags,
                       int use_csr) {
  const int b = blockIdx.x, t = threadIdx.x;
  if (b < 3125) {                      // edge_index passthrough -> out
    int f32m = det_f32((const u16*)x);
    int i64m = !det_i32((const int*)ei);
    int i = b * 256 + t;               // < 800000 exactly
    float v = i64m ? (float)((const long long*)ei)[i] : (float)((const int*)ei)[i];
    stf(out, (size_t)320000 + i, v, f32m);
  } else if (b < 4688) {               // CSR count
    if (!use_csr) return;
    int i64m = !det_i32((const int*)ei);
    int i = (b - 3125) * 256 + t;
    if (i < NE) atomicAdd(&cnt[ldi(ei, NE + i, i64m)], 1);
  } else if (b < 5938) {               // node embedding
    int f32m = det_f32((const u16*)x);
    int i = (b - 4688) * 256 + t;      // < 320000
    int n = i >> 4, d = i & 15;
    float acc = ldf(bn, d, f32m);
    for (int k = 0; k < 16; ++k)
      acc += ldf(x, n * 16 + k, f32m) * ldf(Wn, k * 16 + d, f32m);
    h0[i] = fmaxf(acc, 0.f);
  } else if (b < 5970) {               // pack W2 -> fp8 B-fragment order
    int f32m = det_f32((const u16*)W2);
    int i = (b - 5938) * 256 + t;      // < 8192: i = kb*256 + ks*64 + lane
    int lane = i & 63, ks = (i >> 6) & 3, kb = i >> 8;
    int n = lane & 15, qq = lane >> 4;
    for (int j = 0; j < 8; ++j) {
      int hrow = ks * 32 + qq * 8 + j;
      w2p8[(size_t)i * 8 + j] = f2fp8(ldf(W2, (size_t)hrow * 512 + kb * 16 + n, f32m));
    }
  } else if (b < 5972) {               // pack W1 bf16 (zero-padded K=32)
    int f32m = det_f32((const u16*)W2);
    int i = (b - 5970) * 256 + t;      // < 512
    int lane = i & 63, n = i >> 6;
    int col = n * 16 + (lane & 15), qq = lane >> 4;
    for (int j = 0; j < 8; ++j) {
      int kk = qq * 8 + j;
      w1p[(size_t)i * 8 + j] = (kk < 16) ? f2bf(ldf(W1, (size_t)kk * 128 + col, f32m)) : (u16)0;
    }
  } else if (b < 6036) {               // 64 detect blocks -> flags
    int tt = (b - 5972) * 256 + t;
    int found_f32 = 0, found_hi = 0;
    const u16* x16 = (const u16*)x;
    for (int i = tt; i < NN * 16; i += 64 * 256) {
      u16 v = x16[i];
      if ((v & 0x7F80u) == 0x7F80u) found_f32 = 1;
    }
    const int* e32 = (const int*)ei;
    for (int i = tt; i < 200000; i += 64 * 256)
      if (e32[2 * i + 1] != 0) found_hi = 1;
    if (__any(found_f32) && (t & 63) == 0) atomicOr(&flags[0], 1);
    if (__any(found_hi) && (t & 63) == 0) atomicOr(&flags[1], 1);
  } else {                             // ee + log_softmax -> out
    int f32m = det_f32((const u16*)ea);
    __shared__ float W[256];
    __shared__ float Bv2[16];
    W[t] = ldf(We, t, f32m);
    if (t < 16) Bv2[t] = ldf(be, t, f32m);
    __syncthreads();
    int e = (b - 6036) * 256 + t;
    if (e >= NE) return;
    float v[16];
    if (f32m) {
      const f32x4* ep = (const f32x4*)((const float*)ea + (size_t)e * 16);
      f32x4 r0 = ep[0], r1 = ep[1], r2 = ep[2], r3 = ep[3];
      v[0]=r0.x; v[1]=r0.y; v[2]=r0.z; v[3]=r0.w;
      v[4]=r1.x; v[5]=r1.y; v[6]=r1.z; v[7]=r1.w;
      v[8]=r2.x; v[9]=r2.y; v[10]=r2.z; v[11]=r2.w;
      v[12]=r3.x; v[13]=r3.y; v[14]=r3.z; v[15]=r3.w;
    } else {
      union { u32x4 qv[2]; u16 h[16]; } rw;
      const u32x4* ep = (const u32x4*)((const u16*)ea + (size_t)e * 16);
      rw.qv[0] = ep[0]; rw.qv[1] = ep[1];
#pragma unroll
      for (int k = 0; k < 16; ++k) v[k] = bf2f(rw.h[k]);
    }
    float o[16];
    float mx = 0.f;
#pragma unroll
    for (int d = 0; d < 16; ++d) {
      float acc = Bv2[d];
#pragma unroll
      for (int k = 0; k < 16; ++k) acc += v[k] * W[k * 16 + d];
      acc = fmaxf(acc, 0.f);
      o[d] = acc;
      mx = fmaxf(mx, acc);
    }
    float s = 0.f;
#pragma unroll
    for (int d = 0; d < 16; ++d) s += __expf(o[d] - mx);
    float lse = mx + __logf(s);
    const size_t off_ee = 1120000, off_ls = 7520000;
    if (f32m) {
      union { f32x4 fv; float f[4]; } pe, pl;
      float* oe = (float*)out + off_ee + (size_t)e * 16;
      float* ol = (float*)out + off_ls + (size_t)e * 16;
#pragma unroll
      for (int g = 0; g < 4; ++g) {
#pragma unroll
        for (int d = 0; d < 4; ++d) { pe.f[d] = o[g*4+d]; pl.f[d] = o[g*4+d] - lse; }
        ((f32x4*)oe)[g] = pe.fv;
        ((f32x4*)ol)[g] = pl.fv;
      }
    } else {
      union { u32x4 qv[2]; u16 h[16]; } pe, pl;
#pragma unroll
      for (int d = 0; d < 16; ++d) {
        pe.h[d] = f2bf(o[d]);
        pl.h[d] = f2bf(o[d] - lse);
      }
      u32x4* oe = (u32x4*)((u16*)out + off_ee + (size_t)e * 16);
      u32x4* ol = (u32x4*)((u16*)out + off_ls + (size_t)e * 16);
      oe[0] = pe.qv[0]; oe[1] = pe.qv[1];
      ol[0] = pl.qv[0]; ol[1] = pl.qv[1];
    }
  }
}

// --- K2: exclusive scan over counts -> rowptr, cursor ----------------------
__global__ void k_scan(const int* __restrict__ cnt, int* __restrict__ rowptr,
                       int* __restrict__ cursor) {
  __shared__ int part[1024];
  int t = threadIdx.x;
  int base = t * 20;                               // 1024*20 >= NN
  int s = 0;
  for (int j = 0; j < 20; ++j) { int idx = base + j; if (idx < NN) s += cnt[idx]; }
  part[t] = s;
  __syncthreads();
  for (int off = 1; off < 1024; off <<= 1) {
    int v = (t >= off) ? part[t - off] : 0;
    __syncthreads();
    part[t] += v;
    __syncthreads();
  }
  int run = t ? part[t - 1] : 0;
  for (int j = 0; j < 20; ++j) {
    int idx = base + j;
    if (idx < NN) {
      int c = cnt[idx];                            // read BEFORE aliasing write
      rowptr[idx] = run; cursor[idx] = run; run += c;
    }
  }
  if (t == 1023) rowptr[NN] = part[1023];
}

// --- K3: inv[e] = CSR slot of edge e --------------------------------------
__global__ void k_scatter(const void* __restrict__ ei, int* __restrict__ cursor,
                          int* __restrict__ inv, const int* __restrict__ flags) {
  const int i64m = !flags[1];
  int i = blockIdx.x * 256 + threadIdx.x;
  if (i >= NE) return;
  int d = ldi(ei, NE + i, i64m);
  int pos = atomicAdd(&cursor[d], 1);
  inv[i] = pos;
}

// --- K4/K6: fused edge kernel, one 128-edge tile per block ----------------
__launch_bounds__(256, 4)
__global__ void k_edge(const void* __restrict__ ea, const void* __restrict__ ei,
                       const float* __restrict__ hprev,
                       const u8* __restrict__ w2p8, const u16* __restrict__ w1p,
                       const void* __restrict__ b1, const void* __restrict__ b2,
                       u16* __restrict__ msg16, float* __restrict__ aggr,
                       const int* __restrict__ inv,
                       const int* __restrict__ flags, int use_csr) {
  __shared__ u8    a2_lds[128 * 136];   // 17408 B fp8; stride 136B: 8B-aligned frags
  __shared__ u16   nfT[32 * 132];       //  8448 B bf16; nfT[kb][edge]
  __shared__ float msg_lds[128 * 17];   //  8704 B
  __shared__ int   dst_lds[128];        // 512 B; total 35072 -> 4 blocks/CU

  const int f32m = flags[0], i64m = !flags[1];
  const int t = threadIdx.x;
  const int lane = t & 63, w = t >> 6;
  const int q = lane >> 4, l16 = lane & 15;
  const int e0 = blockIdx.x * 128;

  // hoisted ea A-fragment loads (nontemporal: streamed once, keep w2p L2-hot)
  union { short8 s; u16 h[8]; } ua[2];
#pragma unroll
  for (int mm = 0; mm < 2; ++mm) {
    int m = w * 2 + mm;
    if (q < 2) {
      if (f32m) {
        const f32x4* er = (const f32x4*)((const float*)ea + ((size_t)(e0 + m * 16 + l16) * 16 + q * 8));
        f32x4 f0 = __builtin_nontemporal_load(er);
        f32x4 f1 = __builtin_nontemporal_load(er + 1);
        ua[mm].h[0] = f2bf(f0.x); ua[mm].h[1] = f2bf(f0.y);
        ua[mm].h[2] = f2bf(f0.z); ua[mm].h[3] = f2bf(f0.w);
        ua[mm].h[4] = f2bf(f1.x); ua[mm].h[5] = f2bf(f1.y);
        ua[mm].h[6] = f2bf(f1.z); ua[mm].h[7] = f2bf(f1.w);
      } else {
        ua[mm].s = __builtin_nontemporal_load(
            (const short8*)((const u16*)ea + ((size_t)(e0 + m * 16 + l16) * 16 + q * 8)));
      }
    } else {
#pragma unroll
      for (int j = 0; j < 8; ++j) ua[mm].h[j] = 0;
    }
  }

  float b2v[8], bb[8];
#pragma unroll
  for (int i = 0; i < 8; ++i) {
    b2v[i] = ldf(b2, (w * 8 + i) * 16 + l16, f32m);
    bb[i]  = ldf(b1, i * 16 + l16, f32m);          // b1 in regs: no b1_lds barrier
  }
  short8 W1f[8];
  {
    const short8* w1pf = (const short8*)w1p;
#pragma unroll
    for (int n = 0; n < 8; ++n) W1f[n] = w1pf[n * 64 + lane];
  }

  {  // phase 0: gather nf -> transposed bf16 LDS; dst slot; zero msg
    int e = t >> 1, hh = t & 1;               // hh=0 -> dst, hh=1 -> src
    int node = hh ? ldi(ei, e0 + e, i64m) : ldi(ei, NE + e0 + e, i64m);
    const f32x4* hp = (const f32x4*)(hprev + (size_t)node * 16);
    f32x4 h0v = hp[0], h1v = hp[1], h2v = hp[2], h3v = hp[3];
    u16* col = nfT + (size_t)(hh * 16) * 132 + e;
    col[0 * 132] = f2bf(h0v.x); col[1 * 132] = f2bf(h0v.y);
    col[2 * 132] = f2bf(h0v.z); col[3 * 132] = f2bf(h0v.w);
    col[4 * 132] = f2bf(h1v.x); col[5 * 132] = f2bf(h1v.y);
    col[6 * 132] = f2bf(h1v.z); col[7 * 132] = f2bf(h1v.w);
    col[8 * 132] = f2bf(h2v.x); col[9 * 132] = f2bf(h2v.y);
    col[10 * 132] = f2bf(h2v.z); col[11 * 132] = f2bf(h2v.w);
    col[12 * 132] = f2bf(h3v.x); col[13 * 132] = f2bf(h3v.y);
    col[14 * 132] = f2bf(h3v.z); col[15 * 132] = f2bf(h3v.w);
    if (!hh) {
      if (use_csr) dst_lds[e] = inv[e0 + e];
      else         dst_lds[e] = node;
    }
    float* mz = msg_lds + e * 17 + hh * 8;
#pragma unroll
    for (int k2 = 0; k2 < 8; ++k2) mz[k2] = 0.f;
  }

  // phase 1 (same region, no barrier needed): A2 = relu(ea@W1+b1) -> fp8 LDS
#pragma unroll
  for (int mm = 0; mm < 2; ++mm) {
    int m = w * 2 + mm;
    short8 A = ua[mm].s;
#pragma unroll
    for (int n = 0; n < 8; ++n) {
      f32x4 c = {0.f, 0.f, 0.f, 0.f};
      c = __builtin_amdgcn_mfma_f32_16x16x32_bf16(A, W1f[n], c, 0, 0, 0);
#pragma unroll
      for (int r = 0; r < 4; ++r)
        a2_lds[(m * 16 + q * 4 + r) * 136 + n * 16 + l16] =
            f2fp8(fmaxf(c[r] + bb[n], 0.f));
    }
  }
  __syncthreads();

  // phase 2: fp8 MFMA. kb-chunk outer (2 kb), m inner, mr[8][4] resident.
  // Live: mr 32 + Bc 16 + A 8 + b2v 8 -> ~85 VGPR, no reloads.
  float mr[8][4];
#pragma unroll
  for (int m = 0; m < 8; ++m)
#pragma unroll
    for (int r = 0; r < 4; ++r) mr[m][r] = 0.f;

  const i64t* w2pf = (const i64t*)w2p8;
#pragma unroll 1
  for (int ic = 0; ic < 4; ++ic) {
    i64t Bc[2][4];
#pragma unroll
    for (int ii = 0; ii < 2; ++ii)
#pragma unroll
      for (int ks = 0; ks < 4; ++ks)
        Bc[ii][ks] = w2pf[((w * 8 + ic * 2 + ii) * 4 + ks) * 64 + lane];
#pragma unroll 1
    for (int m = 0; m < 8; ++m) {
      const u8* ar = &a2_lds[(m * 16 + l16) * 136 + q * 8];
      i64t A0 = *(const i64t*)(ar);
      i64t A1 = *(const i64t*)(ar + 32);
      i64t A2f = *(const i64t*)(ar + 64);
      i64t A3 = *(const i64t*)(ar + 96);
#pragma unroll
      for (int ii = 0; ii < 2; ++ii) {
        int i = ic * 2 + ii;
        f32x4 c = {b2v[i], b2v[i], b2v[i], b2v[i]};   // bias rides in C
        c = __builtin_amdgcn_mfma_f32_16x16x32_fp8_fp8(A0, Bc[ii][0], c, 0, 0, 0);
        c = __builtin_amdgcn_mfma_f32_16x16x32_fp8_fp8(A1, Bc[ii][1], c, 0, 0, 0);
        c = __builtin_amdgcn_mfma_f32_16x16x32_fp8_fp8(A2f, Bc[ii][2], c, 0, 0, 0);
        c = __builtin_amdgcn_mfma_f32_16x16x32_fp8_fp8(A3, Bc[ii][3], c, 0, 0, 0);
        int kb = w * 8 + i;
        short4v nf4 = *(const short4v*)&nfT[(size_t)kb * 132 + m * 16 + q * 4];
        mr[m][0] += bf2f((u16)nf4[0]) * c[0];
        mr[m][1] += bf2f((u16)nf4[1]) * c[1];
        mr[m][2] += bf2f((u16)nf4[2]) * c[2];
        mr[m][3] += bf2f((u16)nf4[3]) * c[3];
      }
    }
  }
  // cross-wave kb-reduction: one LDS-atomic block per tile
#pragma unroll
  for (int m = 0; m < 8; ++m) {
    int eb = (m * 16 + q * 4) * 17 + l16;
    atomicAdd(&msg_lds[eb + 0 * 17], mr[m][0]);
    atomicAdd(&msg_lds[eb + 1 * 17], mr[m][1]);
    atomicAdd(&msg_lds[eb + 2 * 17], mr[m][2]);
    atomicAdd(&msg_lds[eb + 3 * 17], mr[m][3]);
  }
  __syncthreads();

  {  // epilogue
    int e = t >> 1, dh = t & 1;
    const float* mp = msg_lds + e * 17 + dh * 8;
    if (use_csr) {  // bf16 msg at CSR slot (nontemporal: consumed next kernel)
      int pos = dst_lds[e];
      union { u32x4 qv; u16 h[8]; } pk;
#pragma unroll
      for (int dd = 0; dd < 8; ++dd) pk.h[dd] = f2bf(mp[dd]);
      __builtin_nontemporal_store(pk.qv, (u32x4*)(msg16 + (size_t)pos * 16 + dh * 8));
    } else {        // fallback: scatter atomics
      int dnode = dst_lds[e];
      float* ap2 = aggr + (size_t)dnode * 16 + dh * 8;
#pragma unroll
      for (int dd = 0; dd < 8; ++dd) atomicAdd(ap2 + dd, mp[dd]);
    }
  }
}

// --- K5/K7: gather + combine: h_new = csr_sum(msg) + h_old @ root + bias --
__global__ void k_gather(const u16* __restrict__ msg16,
                         const int* __restrict__ rowptr,
                         const float* __restrict__ h_old,
                         const void* __restrict__ root,
                         const void* __restrict__ bias,
                         float* __restrict__ h_new, void* __restrict__ out,
                         const int* __restrict__ flags) {
  const int f32m = flags[0];
  __shared__ float R[256];
  __shared__ float Bv[16];
  int tt = threadIdx.x;
  R[tt] = ldf(root, tt, f32m);
  if (tt < 16) Bv[tt] = ldf(bias, tt, f32m);
  __syncthreads();
  int t = blockIdx.x * 256 + tt;
  if (t >= NN * 16) return;
  int n = t >> 4, d = t & 15;
  float acc = Bv[d];
#pragma unroll
  for (int k = 0; k < 16; ++k) acc += h_old[n * 16 + k] * R[k * 16 + d];
  int beg = rowptr[n], end = rowptr[n + 1];
  for (int i = beg; i < end; ++i)          // contiguous bf16 rows
    acc += bf2f(msg16[(size_t)i * 16 + d]);
  if (h_new) h_new[t] = acc;
  else       stf(out, t, acc, f32m);
}

// --- fallback combine (non-CSR path) --------------------------------------
__global__ void k_combine(const float* __restrict__ h_old,
                          const float* __restrict__ aggr,
                          const void* __restrict__ root,
                          const void* __restrict__ bias,
                          float* __restrict__ h_new, void* __restrict__ out,
                          const int* __restrict__ flags) {
  const int f32m = flags[0];
  int t = blockIdx.x * 256 + threadIdx.x;
  if (t >= NN * 16) return;
  int n = t >> 4, d = t & 15;
  float acc = aggr[t] + ldf(bias, d, f32m);
  for (int k = 0; k < 16; ++k)
    acc += h_old[n * 16 + k] * ldf(root, (size_t)k * 16 + d, f32m);
  if (h_new) h_new[t] = acc;
  else       stf(out, t, acc, f32m);
}

extern "C" void kernel_launch(void* const* d_in, const int* in_sizes, int n_in,
                              void* d_out, int out_size, void* d_ws, size_t ws_size,
                              hipStream_t stream) {
  const void* x     = d_in[0];
  const void* ei    = d_in[1];
  const void* ea    = d_in[2];
  const void* Wn    = d_in[3];
  const void* bn    = d_in[4];
  const void* We    = d_in[5];
  const void* be    = d_in[6];
  const void* W1    = d_in[7];
  const void* b1    = d_in[8];
  const void* W2    = d_in[9];
  const void* b2    = d_in[10];
  const void* root1 = d_in[11];
  const void* bias1 = d_in[12];
  const void* root2 = d_in[13];
  const void* bias2 = d_in[14];

  char* ws = (char*)d_ws;
  int*   flags  = (int*)ws;                             // @0, 16 B
  int*   cursor = (int*)(ws + 16);                      //    80,000 B (also cnt)
  float* h0     = (float*)(ws + 80016);                 // 1,280,000 B
  float* h1     = (float*)(ws + 1360016);               // 1,280,000 B
  u8*    w2p8   = (u8*)(ws + 2640016);                  //    65,536 B
  u16*   w1p    = (u16*)(ws + 2705552);                 //     8,192 B
  u16*   msg16  = (u16*)(ws + 2713744);                 // 12,800,000 B
  int*   rowptr = (int*)(ws + 15513744);                //     80,016 B
  int*   inv    = (int*)(ws + 15593760);                //  1,600,000 B
  const size_t need_csr = 17193760;
  float* aggr = (float*)(ws + 2713744);                 // fallback aliases msg16
  const int use_csr = (ws_size >= need_csr) ? 1 : 0;

  hipMemsetAsync(ws, 0, use_csr ? 80016 : 16, stream);
  k_prep<<<7599, 256, 0, stream>>>(x, ei, ea, W1, W2, Wn, bn, We, be,
                                   h0, w2p8, w1p, cursor, d_out, flags, use_csr);

  if (use_csr) {
    k_scan<<<1, 1024, 0, stream>>>(cursor, rowptr, cursor);
    k_scatter<<<1563, 256, 0, stream>>>(ei, cursor, inv, flags);

    k_edge<<<3125, 256, 0, stream>>>(ea, ei, h0, w2p8, w1p, b1, b2, msg16, nullptr, inv, flags, 1);
    k_gather<<<1250, 256, 0, stream>>>(msg16, rowptr, h0, root1, bias1, h1, nullptr, flags);
    k_edge<<<3125, 256, 0, stream>>>(ea, ei, h1, w2p8, w1p, b1, b2, msg16, nullptr, inv, flags, 1);
    k_gather<<<1250, 256, 0, stream>>>(msg16, rowptr, h1, root2, bias2, nullptr, d_out, flags);
  } else {
    hipMemsetAsync(aggr, 0, (size_t)NN * 16 * 4, stream);
    k_edge<<<3125, 256, 0, stream>>>(ea, ei, h0, w2p8, w1p, b1, b2, nullptr, aggr, nullptr, flags, 0);
    k_combine<<<1250, 256, 0, stream>>>(h0, aggr, root1, bias1, h1, nullptr, flags);
    hipMemsetAsync(aggr, 0, (size_t)NN * 16 * 4, stream);
    k_edge<<<3125, 256, 0, stream>>>(ea, ei, h1, w2p8, w1p, b1, b2, nullptr, aggr, nullptr, flags, 0);
    k_combine<<<1250, 256, 0, stream>>>(h1, aggr, root2, bias2, nullptr, d_out, flags);
  }
}